// Round 14
// baseline (127.848 us; speedup 1.0000x reference)
//
#include <hip/hip_runtime.h>
#include <hip/hip_bf16.h>
#include <math.h>

#define N_NODES 16384
#define B_MOL   1024

typedef __attribute__((ext_vector_type(8))) short short8v;
typedef __attribute__((ext_vector_type(4))) float f32x4;

static __device__ __forceinline__ unsigned short f2bf(float f) {
    unsigned int u = __float_as_uint(f);
    unsigned int r = (u + 0x7FFFu + ((u >> 16) & 1u)) >> 16;   // RNE
    return (unsigned short)r;
}
static __device__ __forceinline__ float bf2f(unsigned short h) {
    return __uint_as_float(((unsigned int)h) << 16);
}

// ---------------------------------------------------------------------------
// Pack all weights into MFMA-fragment order, bf16 hi/lo.
// Fragment = (colblk of 16 cols) x (kstep of 32 k): 512 shorts, lane-major:
//   lane = (kk>>3)*16 + (col&15), pos = kk&7.
// frag index = (cb*nK + ks)*2 + hl, each 512 shorts.
// Segments (short offsets): L0 (512x128) @0, L1 @131072, M1 (256x128) @262144,
// M2 (256x256) @327680.
// ---------------------------------------------------------------------------
__global__ __launch_bounds__(256)
void conv_pack(const float* __restrict__ Wl, const float* __restrict__ Wr,
               const float* __restrict__ g1, const float* __restrict__ g2,
               unsigned short* __restrict__ wpk) {
    int idx = blockIdx.x * 256 + threadIdx.x;
    if (idx >= 229376) return;
    float v; size_t base; int nK, k, col;
    if (idx < 131072) {                      // layers 0/1: 512 cols x 128 k
        int l = idx >> 16;
        int e = idx & 65535;
        k = e >> 9; col = e & 511;
        v = (col < 256) ? Wl[l * 32768 + k * 256 + col]
                        : Wr[l * 32768 + k * 256 + (col - 256)];
        base = (size_t)l * 131072; nK = 4;
    } else if (idx < 163840) {               // MLP1: 256 x 128
        int e = idx - 131072; k = e >> 8; col = e & 255;
        v = g1[k * 256 + col]; base = 262144; nK = 4;
    } else {                                 // MLP2: 256 x 256
        int e = idx - 163840; k = e >> 8; col = e & 255;
        v = g2[k * 256 + col]; base = 327680; nK = 8;
    }
    int cb = col >> 4, ci = col & 15, ks = k >> 5, kk = k & 31;
    int lane = ((kk >> 3) << 4) | ci;
    size_t fo = ((size_t)(cb * nK + ks) * 2) * 512 + lane * 8 + (kk & 7);
    unsigned short h = f2bf(v);
    wpk[base + fo] = h;
    wpk[base + fo + 512] = f2bf(v - bf2f(h));
}

// ---------------------------------------------------------------------------
// Wave-tile GEMM, 16 rows x (NCB*16) cols, K = NK*32. A pairs from LDS
// [16][264]; B from frag-packed global (register double-buffered).
// Split-bf16: acc += ah*bh + ah*bl + al*bh.
// ---------------------------------------------------------------------------
template<int NK, int NCB>
static __device__ __forceinline__ void tile_gemm16(
        const short* __restrict__ Ah, const short* __restrict__ Al,
        const unsigned short* __restrict__ wv,
        f32x4 (&acc)[NCB], int lane) {
    int lr = lane & 15;
    int kq = (lane >> 4) * 8;
    short8v bc[NCB][2], bn[NCB][2];
    #pragma unroll
    for (int j = 0; j < NCB; ++j) {
        bc[j][0] = *(const short8v*)&wv[((j * NK + 0) * 2 + 0) * 512 + lane * 8];
        bc[j][1] = *(const short8v*)&wv[((j * NK + 0) * 2 + 1) * 512 + lane * 8];
    }
    #pragma unroll
    for (int ks = 0; ks < NK; ++ks) {
        if (ks + 1 < NK) {
            #pragma unroll
            for (int j = 0; j < NCB; ++j) {
                bn[j][0] = *(const short8v*)&wv[((j * NK + ks + 1) * 2 + 0) * 512 + lane * 8];
                bn[j][1] = *(const short8v*)&wv[((j * NK + ks + 1) * 2 + 1) * 512 + lane * 8];
            }
        }
        int ro = lr * 264 + ks * 32 + kq;
        short8v ah = *(const short8v*)&Ah[ro];
        short8v al = *(const short8v*)&Al[ro];
        #pragma unroll
        for (int j = 0; j < NCB; ++j)
            acc[j] = __builtin_amdgcn_mfma_f32_16x16x32_bf16(ah, bc[j][0], acc[j], 0, 0, 0);
        #pragma unroll
        for (int j = 0; j < NCB; ++j)
            acc[j] = __builtin_amdgcn_mfma_f32_16x16x32_bf16(ah, bc[j][1], acc[j], 0, 0, 0);
        #pragma unroll
        for (int j = 0; j < NCB; ++j)
            acc[j] = __builtin_amdgcn_mfma_f32_16x16x32_bf16(al, bc[j][0], acc[j], 0, 0, 0);
        if (ks + 1 < NK) {
            #pragma unroll
            for (int j = 0; j < NCB; ++j) { bc[j][0] = bn[j][0]; bc[j][1] = bn[j][1]; }
        }
    }
}

static __device__ __forceinline__ void pack_pair(f32x4 o, short4* ph, short4* pl) {
    unsigned short h0 = f2bf(o[0]), h1 = f2bf(o[1]), h2 = f2bf(o[2]), h3 = f2bf(o[3]);
    *ph = make_short4((short)h0, (short)h1, (short)h2, (short)h3);
    *pl = make_short4((short)f2bf(o[0] - bf2f(h0)), (short)f2bf(o[1] - bf2f(h1)),
                      (short)f2bf(o[2] - bf2f(h2)), (short)f2bf(o[3] - bf2f(h3)));
}

// ---------------------------------------------------------------------------
// Whole network, one block per molecule (16 rows), 512 threads (8 waves).
// LDS ~55 KB -> 2 blocks/CU (async overlap). __launch_bounds__(512,1):
// compiler free to use ~120 VGPR (R7 precedent) -> no spills; 2nd-arg >= 3
// proved catastrophic (64-VGPR clamp + 40 MB spill, R8/R10/R11/R13).
// ---------------------------------------------------------------------------
__global__ __launch_bounds__(512, 1)
void mega(const float* __restrict__ H, const unsigned short* __restrict__ wpk,
          const float* __restrict__ bl, const float* __restrict__ br,
          const float* __restrict__ att, const float* __restrict__ gbias,
          const float* __restrict__ gb1, const float* __restrict__ gb2,
          const float* __restrict__ gW3, const float* __restrict__ gb3,
          float* __restrict__ out) {
    __shared__ short sAh[16][264], sAl[16][264];
    __shared__ float sL[16][260], sR[16][260];
    __shared__ float sLog[32][20];
    __shared__ float sAtt[512];
    __shared__ float sg[16], ssc[16];

    int tid  = threadIdx.x;
    int lane = tid & 63;
    int w    = tid >> 6;                 // wave 0..7
    int lr   = lane & 15;
    int mol  = blockIdx.x;
    int rowBase = mol * 16;

    // ---- stage H -> bf16 hi/lo pairs; stage att ----
    {
        int r = tid >> 5, q = tid & 31;
        f32x4 v = *(const f32x4*)&H[(size_t)(rowBase + r) * 128 + q * 4];
        pack_pair(v, (short4*)&sAh[r][q * 4], (short4*)&sAl[r][q * 4]);
        sAtt[tid] = att[tid];
    }
    __syncthreads();

    // ================= 2 GAT layers =================
    for (int l = 0; l < 2; ++l) {
        // ---- xl|xr GEMM: wave w -> 64 cols of [xl(256)|xr(256)], 2 passes ----
        {
            #pragma unroll
            for (int p = 0; p < 2; ++p) {
                f32x4 acc[2];
                acc[0] = (f32x4){0.f, 0.f, 0.f, 0.f};
                acc[1] = (f32x4){0.f, 0.f, 0.f, 0.f};
                int cb0 = w * 4 + p * 2;     // global colblock (of 32)
                tile_gemm16<4, 2>(&sAh[0][0], &sAl[0][0],
                                  wpk + (size_t)l * 131072 + (size_t)cb0 * 4096,
                                  acc, lane);
                float* dst; int cbase; const float* bp;
                if (w < 4) { dst = &sL[0][0]; cbase = w * 64 + p * 32; bp = bl + l * 256; }
                else       { dst = &sR[0][0]; cbase = (w - 4) * 64 + p * 32; bp = br + l * 256; }
                int row0 = (lane >> 4) * 4;
                #pragma unroll
                for (int j = 0; j < 2; ++j) {
                    int cl = cbase + j * 16 + lr;
                    float bv = bp[cl];
                    #pragma unroll
                    for (int t = 0; t < 4; ++t)
                        dst[(row0 + t) * 260 + cl] = acc[j][t] + bv;
                }
            }
        }
        __syncthreads();

        // ---- logits: thread = (hh, db, sb, cq16); 4x4 (d,s) reg tile,
        //      8 channels/thread (2 f32x4 chunks); leaky(x,.2)=.6x+.4|x|;
        //      shfl-reduce over 16 cq lanes -> raw logits in sLog ----
        {
            int hh = tid >> 8;
            int db = (tid >> 6) & 3;
            int sb = (tid >> 4) & 3;
            int cq = tid & 15;
            float ac[4][4];
            #pragma unroll
            for (int di = 0; di < 4; ++di)
                #pragma unroll
                for (int si = 0; si < 4; ++si) ac[di][si] = 0.f;
            #pragma unroll
            for (int t = 0; t < 2; ++t) {
                int c4 = cq + 16 * t;
                f32x4 av = *(const f32x4*)&sAtt[l * 256 + hh * 128 + c4 * 4];
                f32x4 a6 = av * 0.6f, a4 = av * 0.4f;
                f32x4 xrv[4], xlv[4];
                #pragma unroll
                for (int di = 0; di < 4; ++di)
                    xrv[di] = *(const f32x4*)&sR[db * 4 + di][hh * 128 + c4 * 4];
                #pragma unroll
                for (int si = 0; si < 4; ++si)
                    xlv[si] = *(const f32x4*)&sL[sb * 4 + si][hh * 128 + c4 * 4];
                #pragma unroll
                for (int di = 0; di < 4; ++di)
                    #pragma unroll
                    for (int si = 0; si < 4; ++si) {
                        f32x4 e = xlv[si] + xrv[di];
                        ac[di][si] += a6[0] * e[0] + a4[0] * fabsf(e[0])
                                    + a6[1] * e[1] + a4[1] * fabsf(e[1])
                                    + a6[2] * e[2] + a4[2] * fabsf(e[2])
                                    + a6[3] * e[3] + a4[3] * fabsf(e[3]);
                    }
            }
            #pragma unroll
            for (int di = 0; di < 4; ++di)
                #pragma unroll
                for (int si = 0; si < 4; ++si) {
                    float v = ac[di][si];
                    v += __shfl_down(v, 8, 16);
                    v += __shfl_down(v, 4, 16);
                    v += __shfl_down(v, 2, 16);
                    v += __shfl_down(v, 1, 16);
                    if (cq == 0)
                        sLog[(db * 4 + di) * 2 + hh][sb * 4 + si] = v;
                }
        }
        __syncthreads();

        // ---- aggregation + inline per-d softmax: thread = (d, cw32);
        //      softmax recomputed redundantly per thread (broadcast reads);
        //      s rotated: se=(s+2cw)&15 -> uniform superbank spread ----
        {
            int d  = tid >> 5;
            int cw = tid & 31;
            f32x4 f0 = (f32x4){0.f, 0.f, 0.f, 0.f};
            #pragma unroll
            for (int hh = 0; hh < 2; ++hh) {
                const float* lg = &sLog[d * 2 + hh][0];
                float mx = lg[0];
                #pragma unroll
                for (int s = 1; s < 16; ++s) mx = fmaxf(mx, lg[s]);
                float al[16];
                float den = 0.f;
                #pragma unroll
                for (int s = 0; s < 16; ++s) { al[s] = expf(lg[s] - mx); den += al[s]; }
                float inv = 1.f / den;
                #pragma unroll
                for (int s = 0; s < 16; ++s) {
                    int se = (s + 2 * cw) & 15;
                    f0 += (al[se] * inv) * *(const f32x4*)&sL[se][hh * 128 + cw * 4];
                }
            }
            f32x4 o = f0 * 0.5f + *(const f32x4*)&gbias[l * 128 + cw * 4];
            pack_pair(o, (short4*)&sAh[d][cw * 4], (short4*)&sAl[d][cw * 4]);
            if (l == 1)
                *(f32x4*)&sR[d][128 + cw * 4] = o;   // stash fp32 X (xr dead)
        }
        __syncthreads();
    }

    // ================= gate MLP =================
    // MLP1: h1 = leaky(X@gW1+gb1, .01) -> pairs back into sAh/sAl
    {
        f32x4 acc[2];
        acc[0] = (f32x4){0.f, 0.f, 0.f, 0.f};
        acc[1] = (f32x4){0.f, 0.f, 0.f, 0.f};
        tile_gemm16<4, 2>(&sAh[0][0], &sAl[0][0],
                          wpk + 262144 + (size_t)w * 8192, acc, lane);
        __syncthreads();   // drain A reads before overwrite
        int row0 = (lane >> 4) * 4;
        #pragma unroll
        for (int j = 0; j < 2; ++j) {
            int cl = w * 32 + j * 16 + lr;
            float bv = gb1[cl];
            #pragma unroll
            for (int t = 0; t < 4; ++t) {
                float v = acc[j][t] + bv;
                v = v >= 0.f ? v : 0.01f * v;
                unsigned short h = f2bf(v);
                sAh[row0 + t][cl] = (short)h;
                sAl[row0 + t][cl] = (short)f2bf(v - bf2f(h));
            }
        }
    }
    __syncthreads();

    // MLP2: h2 = leaky(h1@gW2+gb2, .01) -> sL fp32 (sL dead after agg)
    {
        f32x4 acc[2];
        acc[0] = (f32x4){0.f, 0.f, 0.f, 0.f};
        acc[1] = (f32x4){0.f, 0.f, 0.f, 0.f};
        tile_gemm16<8, 2>(&sAh[0][0], &sAl[0][0],
                          wpk + 327680 + (size_t)w * 16384, acc, lane);
        int row0 = (lane >> 4) * 4;
        #pragma unroll
        for (int j = 0; j < 2; ++j) {
            int cl = w * 32 + j * 16 + lr;
            float bv = gb2[cl];
            #pragma unroll
            for (int t = 0; t < 4; ++t) {
                float v = acc[j][t] + bv;
                v = v >= 0.f ? v : 0.01f * v;
                sL[row0 + t][cl] = v;
            }
        }
    }
    __syncthreads();

    // ---- gate dot: g[row] = h2[row]·gW3 + gb3 (32 lanes x 8 ch) ----
    {
        int grow = tid >> 5, l32 = tid & 31;
        f32x4 h2a = *(const f32x4*)&sL[grow][l32 * 8];
        f32x4 h2b = *(const f32x4*)&sL[grow][l32 * 8 + 4];
        f32x4 w3a = *(const f32x4*)&gW3[l32 * 8];
        f32x4 w3b = *(const f32x4*)&gW3[l32 * 8 + 4];
        float p = h2a[0] * w3a[0] + h2a[1] * w3a[1] + h2a[2] * w3a[2] + h2a[3] * w3a[3]
                + h2b[0] * w3b[0] + h2b[1] * w3b[1] + h2b[2] * w3b[2] + h2b[3] * w3b[3];
        #pragma unroll
        for (int off = 16; off; off >>= 1) p += __shfl_down(p, off, 32);
        if (l32 == 0) sg[grow] = p + gb3[0];
    }
    __syncthreads();

    // ---- segment softmax (16-wide) + scores ----
    if (tid < 16) {
        float v = sg[tid];
        float mx = v;
        #pragma unroll
        for (int off = 8; off; off >>= 1) mx = fmaxf(mx, __shfl_xor(mx, off, 16));
        float e = expf(v - mx);
        float den = e;
        #pragma unroll
        for (int off = 8; off; off >>= 1) den += __shfl_xor(den, off, 16);
        float sc = e / den;
        ssc[tid] = sc;
        out[131072 + rowBase + tid] = sc;
    }
    __syncthreads();

    // ---- pool: h_pool[mol] = sum_s score[s]*X[s] (X in sR cols 128..255) ----
    if (tid < 128) {
        float a = 0.f;
        #pragma unroll
        for (int s = 0; s < 16; ++s)
            a += ssc[s] * sR[s][128 + tid];
        out[(size_t)mol * 128 + tid] = a;
    }
}

// ---------------------------------------------------------------------------
extern "C" void kernel_launch(void* const* d_in, const int* in_sizes, int n_in,
                              void* d_out, int out_size, void* d_ws, size_t ws_size,
                              hipStream_t stream) {
    (void)in_sizes; (void)n_in; (void)out_size; (void)ws_size;
    const float* H        = (const float*)d_in[0];
    const float* Wl       = (const float*)d_in[4];
    const float* bl       = (const float*)d_in[5];
    const float* Wr       = (const float*)d_in[6];
    const float* br       = (const float*)d_in[7];
    const float* att      = (const float*)d_in[8];
    const float* gat_bias = (const float*)d_in[9];
    const float* gW1      = (const float*)d_in[10];
    const float* gb1      = (const float*)d_in[11];
    const float* gW2      = (const float*)d_in[12];
    const float* gb2      = (const float*)d_in[13];
    const float* gW3      = (const float*)d_in[14];
    const float* gb3      = (const float*)d_in[15];
    float* out = (float*)d_out;

    unsigned short* wpk = (unsigned short*)d_ws;   // 458752 shorts

    conv_pack<<<896, 256, 0, stream>>>(Wl, Wr, gW1, gW2, wpk);
    mega<<<B_MOL, 512, 0, stream>>>(H, wpk, bl, br, att, gat_bias,
                                    gb1, gb2, gW3, gb3, out);
}

// Round 15
// 67.357 us; speedup vs baseline: 1.8981x; 1.8981x over previous
//
#include <hip/hip_runtime.h>
#include <hip/hip_bf16.h>
#include <math.h>

#define N_NODES 16384
#define B_MOL   1024

typedef __attribute__((ext_vector_type(8))) short short8v;
typedef __attribute__((ext_vector_type(4))) float f32x4;

static __device__ __forceinline__ unsigned short f2bf(float f) {
    unsigned int u = __float_as_uint(f);
    unsigned int r = (u + 0x7FFFu + ((u >> 16) & 1u)) >> 16;   // RNE
    return (unsigned short)r;
}
static __device__ __forceinline__ float bf2f(unsigned short h) {
    return __uint_as_float(((unsigned int)h) << 16);
}

// ---------------------------------------------------------------------------
// Pack all weights into MFMA-fragment order, bf16 hi/lo.
// Fragment = (colblk of 16 cols) x (kstep of 32 k): 512 shorts, lane-major:
//   lane = (kk>>3)*16 + (col&15), pos = kk&7.
// frag index = (cb*nK + ks)*2 + hl, each 512 shorts.
// Segments (short offsets): L0 (512x128) @0, L1 @131072, M1 (256x128) @262144,
// M2 (256x256) @327680.
// ---------------------------------------------------------------------------
__global__ __launch_bounds__(256)
void conv_pack(const float* __restrict__ Wl, const float* __restrict__ Wr,
               const float* __restrict__ g1, const float* __restrict__ g2,
               unsigned short* __restrict__ wpk) {
    int idx = blockIdx.x * 256 + threadIdx.x;
    if (idx >= 229376) return;
    float v; size_t base; int nK, k, col;
    if (idx < 131072) {                      // layers 0/1: 512 cols x 128 k
        int l = idx >> 16;
        int e = idx & 65535;
        k = e >> 9; col = e & 511;
        v = (col < 256) ? Wl[l * 32768 + k * 256 + col]
                        : Wr[l * 32768 + k * 256 + (col - 256)];
        base = (size_t)l * 131072; nK = 4;
    } else if (idx < 163840) {               // MLP1: 256 x 128
        int e = idx - 131072; k = e >> 8; col = e & 255;
        v = g1[k * 256 + col]; base = 262144; nK = 4;
    } else {                                 // MLP2: 256 x 256
        int e = idx - 163840; k = e >> 8; col = e & 255;
        v = g2[k * 256 + col]; base = 327680; nK = 8;
    }
    int cb = col >> 4, ci = col & 15, ks = k >> 5, kk = k & 31;
    int lane = ((kk >> 3) << 4) | ci;
    size_t fo = ((size_t)(cb * nK + ks) * 2) * 512 + lane * 8 + (kk & 7);
    unsigned short h = f2bf(v);
    wpk[base + fo] = h;
    wpk[base + fo + 512] = f2bf(v - bf2f(h));
}

// ---------------------------------------------------------------------------
// Wave-tile GEMM, 32 rows x (NCB*16) cols, K = NK*32. A pairs from LDS
// (stride 264 shorts); B from frag-packed global (register double-buffered).
// Split-bf16: acc += ah*bh + ah*bl + al*bh.
// ---------------------------------------------------------------------------
template<int NK, int NCB>
static __device__ __forceinline__ void tile_gemm32(
        const short* __restrict__ Ah, const short* __restrict__ Al,
        const unsigned short* __restrict__ wv,
        f32x4 (&acc)[2][NCB], int lane) {
    int lr = lane & 15;
    int kq = (lane >> 4) * 8;
    short8v bc[NCB][2], bn[NCB][2];
    #pragma unroll
    for (int j = 0; j < NCB; ++j) {
        bc[j][0] = *(const short8v*)&wv[((j * NK + 0) * 2 + 0) * 512 + lane * 8];
        bc[j][1] = *(const short8v*)&wv[((j * NK + 0) * 2 + 1) * 512 + lane * 8];
    }
    #pragma unroll
    for (int ks = 0; ks < NK; ++ks) {
        if (ks + 1 < NK) {
            #pragma unroll
            for (int j = 0; j < NCB; ++j) {
                bn[j][0] = *(const short8v*)&wv[((j * NK + ks + 1) * 2 + 0) * 512 + lane * 8];
                bn[j][1] = *(const short8v*)&wv[((j * NK + ks + 1) * 2 + 1) * 512 + lane * 8];
            }
        }
        short8v ah[2], al[2];
        #pragma unroll
        for (int i = 0; i < 2; ++i) {
            int ro = (i * 16 + lr) * 264 + ks * 32 + kq;
            ah[i] = *(const short8v*)&Ah[ro];
            al[i] = *(const short8v*)&Al[ro];
        }
        #pragma unroll
        for (int i = 0; i < 2; ++i)
            #pragma unroll
            for (int j = 0; j < NCB; ++j) {
                acc[i][j] = __builtin_amdgcn_mfma_f32_16x16x32_bf16(ah[i], bc[j][0], acc[i][j], 0, 0, 0);
                acc[i][j] = __builtin_amdgcn_mfma_f32_16x16x32_bf16(ah[i], bc[j][1], acc[i][j], 0, 0, 0);
                acc[i][j] = __builtin_amdgcn_mfma_f32_16x16x32_bf16(al[i], bc[j][0], acc[i][j], 0, 0, 0);
            }
        if (ks + 1 < NK) {
            #pragma unroll
            for (int j = 0; j < NCB; ++j) { bc[j][0] = bn[j][0]; bc[j][1] = bn[j][1]; }
        }
    }
}

static __device__ __forceinline__ void pack_pair(f32x4 o, short4* ph, short4* pl) {
    unsigned short h0 = f2bf(o[0]), h1 = f2bf(o[1]), h2 = f2bf(o[2]), h3 = f2bf(o[3]);
    *ph = make_short4((short)h0, (short)h1, (short)h2, (short)h3);
    *pl = make_short4((short)f2bf(o[0] - bf2f(h0)), (short)f2bf(o[1] - bf2f(h1)),
                      (short)f2bf(o[2] - bf2f(h2)), (short)f2bf(o[3] - bf2f(h3)));
}

// ---------------------------------------------------------------------------
// Whole network, one block per 2 molecules (32 rows), 512 threads (8 waves).
// R7-champion structure + fused logit-softmax + sH1 buffer (no mid-barrier)
// + X stash in sR (no sXf). LDS ~141.6 KB -> 1 block/CU.
// __launch_bounds__(512,1): ~120 VGPR, no spills (2nd arg >=3 clamps to 64
// VGPR and spills catastrophically -- R8/R10/R11/R13 evidence).
// ---------------------------------------------------------------------------
__global__ __launch_bounds__(512, 1)
void mega(const float* __restrict__ H, const unsigned short* __restrict__ wpk,
          const float* __restrict__ bl, const float* __restrict__ br,
          const float* __restrict__ att, const float* __restrict__ gbias,
          const float* __restrict__ gb1, const float* __restrict__ gb2,
          const float* __restrict__ gW3, const float* __restrict__ gb3,
          float* __restrict__ out) {
    __shared__ short sAh[32][264], sAl[32][264];   // X pairs (GEMM/MLP1 A)
    __shared__ short sH1h[32][264], sH1l[32][264]; // h1 pairs (MLP2 A)
    __shared__ float sL[32][260], sR[32][260];     // xl / xr; later h2 / X-stash
    __shared__ float sLog[2][32][20];              // alphas
    __shared__ float sAtt[512];
    __shared__ float sg[32], ssc[32];

    int tid  = threadIdx.x;
    int lane = tid & 63;
    int w    = tid >> 6;                 // wave 0..7
    int lr   = lane & 15;
    int rowBase = blockIdx.x * 32;

    // ---- stage H -> bf16 hi/lo pairs; stage att ----
    {
        int r = tid >> 4, q = tid & 15;
        const float* hp = H + (size_t)(rowBase + r) * 128 + q * 8;
        #pragma unroll
        for (int u = 0; u < 2; ++u) {
            f32x4 v = *(const f32x4*)&hp[u * 4];
            pack_pair(v, (short4*)&sAh[r][q * 8 + u * 4], (short4*)&sAl[r][q * 8 + u * 4]);
        }
        sAtt[tid] = att[tid];
    }
    __syncthreads();

    // ================= 2 GAT layers =================
    for (int l = 0; l < 2; ++l) {
        // ---- xl|xr GEMM: wave w covers 64 cols of [xl(256)|xr(256)] ----
        {
            f32x4 acc[2][4];
            #pragma unroll
            for (int i = 0; i < 2; ++i)
                #pragma unroll
                for (int j = 0; j < 4; ++j) acc[i][j] = (f32x4){0.f, 0.f, 0.f, 0.f};
            tile_gemm32<4, 4>(&sAh[0][0], &sAl[0][0],
                              wpk + (size_t)l * 131072 + (size_t)w * 16384, acc, lane);
            float* dst; int cbase; const float* bp;
            if (w < 4) { dst = &sL[0][0]; cbase = w * 64; bp = bl + l * 256 + w * 64; }
            else       { dst = &sR[0][0]; cbase = (w - 4) * 64; bp = br + l * 256 + (w - 4) * 64; }
            #pragma unroll
            for (int i = 0; i < 2; ++i) {
                int row0 = i * 16 + (lane >> 4) * 4;
                #pragma unroll
                for (int j = 0; j < 4; ++j) {
                    int cl = j * 16 + lr;
                    float bv = bp[cl];
                    #pragma unroll
                    for (int t = 0; t < 4; ++t)
                        dst[(row0 + t) * 260 + cbase + cl] = acc[i][j][t] + bv;
                }
            }
        }
        __syncthreads();

        // ---- logits + FUSED softmax: thread = (m2, hh, db, sb, cq8);
        //      4x4 (d,s) reg tile, 16 ch/thread; leaky(x,.2)=.6x+.4|x|;
        //      shfl_xor cq-reduce, then softmax over s via in-reg si max/sum
        //      + shfl_xor(8,16) across sb lanes. One barrier total. ----
        {
            int m2l = tid >> 8;
            int r8  = tid & 255;
            int hh  = r8 >> 7;
            int db  = (r8 >> 5) & 3;
            int sb  = (r8 >> 3) & 3;
            int cq  = r8 & 7;
            float ac[4][4];
            #pragma unroll
            for (int di = 0; di < 4; ++di)
                #pragma unroll
                for (int si = 0; si < 4; ++si) ac[di][si] = 0.f;
            #pragma unroll
            for (int t = 0; t < 4; ++t) {
                int c4 = cq + 8 * t;
                f32x4 av = *(const f32x4*)&sAtt[l * 256 + hh * 128 + c4 * 4];
                f32x4 a6 = av * 0.6f, a4 = av * 0.4f;
                f32x4 xrv[4], xlv[4];
                #pragma unroll
                for (int di = 0; di < 4; ++di)
                    xrv[di] = *(const f32x4*)&sR[m2l * 16 + db * 4 + di][hh * 128 + c4 * 4];
                #pragma unroll
                for (int si = 0; si < 4; ++si)
                    xlv[si] = *(const f32x4*)&sL[m2l * 16 + sb * 4 + si][hh * 128 + c4 * 4];
                #pragma unroll
                for (int di = 0; di < 4; ++di)
                    #pragma unroll
                    for (int si = 0; si < 4; ++si) {
                        f32x4 e = xlv[si] + xrv[di];
                        ac[di][si] += a6[0] * e[0] + a4[0] * fabsf(e[0])
                                    + a6[1] * e[1] + a4[1] * fabsf(e[1])
                                    + a6[2] * e[2] + a4[2] * fabsf(e[2])
                                    + a6[3] * e[3] + a4[3] * fabsf(e[3]);
                    }
            }
            // cq-reduce (broadcast to all 8 cq lanes)
            #pragma unroll
            for (int di = 0; di < 4; ++di)
                #pragma unroll
                for (int si = 0; si < 4; ++si) {
                    float v = ac[di][si];
                    v += __shfl_xor(v, 4);
                    v += __shfl_xor(v, 2);
                    v += __shfl_xor(v, 1);
                    ac[di][si] = v;
                }
            // fused softmax over s = (sb, si), per di
            #pragma unroll
            for (int di = 0; di < 4; ++di) {
                float mx = fmaxf(fmaxf(ac[di][0], ac[di][1]),
                                 fmaxf(ac[di][2], ac[di][3]));
                mx = fmaxf(mx, __shfl_xor(mx, 8));
                mx = fmaxf(mx, __shfl_xor(mx, 16));
                float e0 = expf(ac[di][0] - mx);
                float e1 = expf(ac[di][1] - mx);
                float e2 = expf(ac[di][2] - mx);
                float e3 = expf(ac[di][3] - mx);
                float den = e0 + e1 + e2 + e3;
                den += __shfl_xor(den, 8);
                den += __shfl_xor(den, 16);
                float inv = 1.f / den;
                if (cq == 0) {
                    float* dstp = &sLog[m2l][(db * 4 + di) * 2 + hh][sb * 4];
                    dstp[0] = e0 * inv; dstp[1] = e1 * inv;
                    dstp[2] = e2 * inv; dstp[3] = e3 * inv;
                }
            }
        }
        __syncthreads();

        // ---- aggregation: thread = (m2, d, cw16); s rotated by cw ----
        {
            int m2a = tid >> 8;
            int d  = (tid >> 4) & 15;
            int cw = tid & 15;
            f32x4 f0 = (f32x4){0.f, 0.f, 0.f, 0.f};
            f32x4 f1 = (f32x4){0.f, 0.f, 0.f, 0.f};
            #pragma unroll
            for (int hh = 0; hh < 2; ++hh) {
                const float* alr = &sLog[m2a][d * 2 + hh][0];
                #pragma unroll
                for (int s = 0; s < 16; ++s) {
                    int se = (s + cw) & 15;
                    float al = alr[se];
                    const float* xp = &sL[m2a * 16 + se][hh * 128 + cw * 8];
                    f0 += al * *(const f32x4*)xp;
                    f1 += al * *(const f32x4*)(xp + 4);
                }
            }
            f32x4 o0 = f0 * 0.5f + *(const f32x4*)&gbias[l * 128 + cw * 8];
            f32x4 o1 = f1 * 0.5f + *(const f32x4*)&gbias[l * 128 + cw * 8 + 4];
            int row = m2a * 16 + d;
            pack_pair(o0, (short4*)&sAh[row][cw * 8],     (short4*)&sAl[row][cw * 8]);
            pack_pair(o1, (short4*)&sAh[row][cw * 8 + 4], (short4*)&sAl[row][cw * 8 + 4]);
            if (l == 1) {   // stash fp32 X in sR cols 128..255 (xr dead)
                *(f32x4*)&sR[row][128 + cw * 8]     = o0;
                *(f32x4*)&sR[row][128 + cw * 8 + 4] = o1;
            }
        }
        __syncthreads();
    }

    // ================= gate MLP =================
    // MLP1: h1 = leaky(X@gW1+gb1, .01) -> pairs into sH1 (no mid-barrier)
    {
        f32x4 acc[2][2];
        #pragma unroll
        for (int i = 0; i < 2; ++i)
            #pragma unroll
            for (int j = 0; j < 2; ++j) acc[i][j] = (f32x4){0.f, 0.f, 0.f, 0.f};
        tile_gemm32<4, 2>(&sAh[0][0], &sAl[0][0],
                          wpk + 262144 + (size_t)w * 8192, acc, lane);
        #pragma unroll
        for (int i = 0; i < 2; ++i) {
            int row0 = i * 16 + (lane >> 4) * 4;
            #pragma unroll
            for (int j = 0; j < 2; ++j) {
                int cl = w * 32 + j * 16 + lr;
                float bv = gb1[cl];
                #pragma unroll
                for (int t = 0; t < 4; ++t) {
                    float v = acc[i][j][t] + bv;
                    v = v >= 0.f ? v : 0.01f * v;
                    unsigned short h = f2bf(v);
                    sH1h[row0 + t][cl] = (short)h;
                    sH1l[row0 + t][cl] = (short)f2bf(v - bf2f(h));
                }
            }
        }
    }
    __syncthreads();

    // MLP2: h2 = leaky(h1@gW2+gb2, .01) -> sL fp32 (sL dead after agg)
    {
        f32x4 acc[2][2];
        #pragma unroll
        for (int i = 0; i < 2; ++i)
            #pragma unroll
            for (int j = 0; j < 2; ++j) acc[i][j] = (f32x4){0.f, 0.f, 0.f, 0.f};
        tile_gemm32<8, 2>(&sH1h[0][0], &sH1l[0][0],
                          wpk + 327680 + (size_t)w * 16384, acc, lane);
        #pragma unroll
        for (int i = 0; i < 2; ++i) {
            int row0 = i * 16 + (lane >> 4) * 4;
            #pragma unroll
            for (int j = 0; j < 2; ++j) {
                int cl = w * 32 + j * 16 + lr;
                float bv = gb2[cl];
                #pragma unroll
                for (int t = 0; t < 4; ++t) {
                    float v = acc[i][j][t] + bv;
                    v = v >= 0.f ? v : 0.01f * v;
                    sL[row0 + t][cl] = v;
                }
            }
        }
    }
    __syncthreads();

    // ---- gate dot: g[row] = h2[row]·gW3 + gb3 (16 lanes x 16 ch) ----
    {
        int grow = tid >> 4, l16 = tid & 15;
        float p = 0.f;
        #pragma unroll
        for (int u = 0; u < 4; ++u) {
            f32x4 h2v = *(const f32x4*)&sL[grow][l16 * 16 + u * 4];
            f32x4 w3v = *(const f32x4*)&gW3[l16 * 16 + u * 4];
            p += h2v[0] * w3v[0] + h2v[1] * w3v[1] + h2v[2] * w3v[2] + h2v[3] * w3v[3];
        }
        p += __shfl_down(p, 8, 16);
        p += __shfl_down(p, 4, 16);
        p += __shfl_down(p, 2, 16);
        p += __shfl_down(p, 1, 16);
        if (l16 == 0) sg[grow] = p + gb3[0];
    }
    __syncthreads();

    // ---- segment softmax (16-wide) + scores ----
    if (tid < 32) {
        float v = sg[tid];
        float mx = v;
        #pragma unroll
        for (int off = 8; off; off >>= 1) mx = fmaxf(mx, __shfl_xor(mx, off, 16));
        float e = expf(v - mx);
        float den = e;
        #pragma unroll
        for (int off = 8; off; off >>= 1) den += __shfl_xor(den, off, 16);
        float sc = e / den;
        ssc[tid] = sc;
        out[131072 + rowBase + tid] = sc;
    }
    __syncthreads();

    // ---- pool: h_pool[mol] = sum_s score[s]*X[s] (X in sR cols 128..255) ----
    if (tid < 256) {
        int cc = tid & 127;
        int mp = tid >> 7;
        float a = 0.f;
        #pragma unroll
        for (int s = 0; s < 16; ++s)
            a += ssc[mp * 16 + s] * sR[mp * 16 + s][128 + cc];
        out[(size_t)(blockIdx.x * 2 + mp) * 128 + cc] = a;
    }
}

// ---------------------------------------------------------------------------
extern "C" void kernel_launch(void* const* d_in, const int* in_sizes, int n_in,
                              void* d_out, int out_size, void* d_ws, size_t ws_size,
                              hipStream_t stream) {
    (void)in_sizes; (void)n_in; (void)out_size; (void)ws_size;
    const float* H        = (const float*)d_in[0];
    const float* Wl       = (const float*)d_in[4];
    const float* bl       = (const float*)d_in[5];
    const float* Wr       = (const float*)d_in[6];
    const float* br       = (const float*)d_in[7];
    const float* att      = (const float*)d_in[8];
    const float* gat_bias = (const float*)d_in[9];
    const float* gW1      = (const float*)d_in[10];
    const float* gb1      = (const float*)d_in[11];
    const float* gW2      = (const float*)d_in[12];
    const float* gb2      = (const float*)d_in[13];
    const float* gW3      = (const float*)d_in[14];
    const float* gb3      = (const float*)d_in[15];
    float* out = (float*)d_out;

    unsigned short* wpk = (unsigned short*)d_ws;   // 458752 shorts

    conv_pack<<<896, 256, 0, stream>>>(Wl, Wr, gW1, gW2, wpk);
    mega<<<B_MOL / 2, 512, 0, stream>>>(H, wpk, bl, br, att, gat_bias,
                                        gb1, gb2, gW3, gb3, out);
}